// Round 9
// baseline (250.542 us; speedup 1.0000x reference)
//
#include <hip/hip_runtime.h>
#include <math.h>

// B=4, X=128, T=256, HIDDEN=128, EMB=128, DH=32, LATENT=32, K=1024
// Outputs concat: u (131072), zt (1048576), px (524288)
// u[b,t,x] = K0 + sum_k zt[b,t,k]*px[b,x,k]*wc[k>>5]   (wc = wcd/32)
//
// Single fused kernel, 512 blocks x 256 thr, one device barrier.
// ws: [0..31] wc, [32] K0, [40] barrier counter (reset via hipMemsetAsync).

#define NB 512

struct P {
    const float *x, *t, *param;
    const float *p2e_W1, *p2e_b1, *p2e_W2, *p2e_b2;
    const float *e2ex_W, *e2ex_b, *e2et_W, *e2et_b;
    const float *px_Wx, *px_bx, *px_We, *px_be, *px_Wo, *px_bo, *px_mult;
    const float *zt_Wx, *zt_bx, *zt_We, *zt_be, *zt_Wo, *zt_bo, *zt_mult;
    const float *h0, *blk_W1, *blk_b1, *blk_Wc, *blk_bc, *blk_W2, *blk_b2;
    const float *d_W, *d_b;
    float *out_u, *out_zt, *out_px, *ws;
    int *bar;
};

__device__ __forceinline__ void fma4(float4& a, float s, const float4& v) {
    a.x += s * v.x; a.y += s * v.y; a.z += s * v.z; a.w += s * v.w;
}

__global__ __launch_bounds__(256, 2) void fused_kernel(P p) {
    __shared__ float4 arena4[2080];     // 33.28 KB, phase-aliased
    __shared__ float wcs[32];
    float* arena = (float*)arena4;
    const int tid = threadIdx.x;
    const int bid = blockIdx.x;

    if (bid < 384) {
        // ================= feat =================
        const bool is_zt = bid >= 128;
        const int un = is_zt ? bid - 128 : bid;
        const int rt = un >> 1, cs = un & 1;
        const int r0 = rt * 8;
        const int b = is_zt ? (r0 >> 8) : (r0 >> 7);

        const float* Wh = is_zt ? p.e2et_W : p.e2ex_W;
        const float* bh = is_zt ? p.e2et_b : p.e2ex_b;
        const float* We = is_zt ? p.zt_We : p.px_We;
        const float* be = is_zt ? p.zt_be : p.px_be;
        const float* Wx = is_zt ? p.zt_Wx : p.px_Wx;
        const float* bxv = is_zt ? p.zt_bx : p.px_bx;
        const float* Wo = is_zt ? p.zt_Wo : p.px_Wo;
        const float* bo = is_zt ? p.zt_bo : p.px_bo;
        const float* coord = is_zt ? p.t : p.x;
        const float mult = is_zt ? p.zt_mult[0] : p.px_mult[0];
        float* outp = is_zt ? p.out_zt : p.out_px;

        const int j = tid & 127;
        const int s = tid >> 7;
        const int k0s = s * 64;
        float* hvA = arena;            // 128
        float* hvB = arena + 128;      // 128
        float* pp  = arena + 256;      // 2*128
        float* f   = arena + 512;      // 8*128

        // ---- per-block g chain (2-way k-sliced, batched loads) ----
        if (s == 0) {
            float a = p.p2e_b1[j];
            #pragma unroll
            for (int q = 0; q < 16; ++q)
                a += p.param[b * 16 + q] * p.p2e_W1[q * 128 + j];
            hvA[j] = __sinf(a);
        }
        __syncthreads();
        {
            float acc = 0.f;
            #pragma unroll 32
            for (int k = 0; k < 64; ++k)
                acc += hvA[k0s + k] * p.p2e_W2[(k0s + k) * 128 + j];
            pp[s * 128 + j] = acc;
        }
        __syncthreads();
        if (s == 0) hvB[j] = pp[j] + pp[128 + j] + p.p2e_b2[j];
        __syncthreads();
        {
            float acc = 0.f;
            #pragma unroll 32
            for (int k = 0; k < 64; ++k)
                acc += hvB[k0s + k] * Wh[(k0s + k) * 128 + j];
            pp[s * 128 + j] = acc;
        }
        __syncthreads();
        if (s == 0) hvA[j] = pp[j] + pp[128 + j] + bh[j];
        __syncthreads();
        {
            float acc = 0.f;
            #pragma unroll 32
            for (int k = 0; k < 64; ++k)
                acc += hvA[k0s + k] * We[(k0s + k) * 128 + j];
            pp[s * 128 + j] = acc;
        }
        __syncthreads();
        if (s == 0) {
            const float g = pp[j] + pp[128 + j] + be[j];
            const float wxj = Wx[j], bxj = bxv[j];
            #pragma unroll
            for (int rr = 0; rr < 8; ++rr)
                f[rr * 128 + j] = __sinf(coord[r0 + rr] * wxj + bxj) * g;
        }
        __syncthreads();

        // ---- GEMM 8 rows x 512 cols: thread (c, h): rows h*4..h*4+3 ----
        const int c = tid & 127;
        const int h = tid >> 7;
        const int c0 = cs * 512 + c * 4;
        const float* wp = Wo + c0;
        const float* fr = f + h * 4 * 128;

        float4 acc[4];
        #pragma unroll
        for (int rr = 0; rr < 4; ++rr) acc[rr] = make_float4(0.f, 0.f, 0.f, 0.f);

        float4 wA[8], wB[8];
        #pragma unroll
        for (int i = 0; i < 8; ++i) wA[i] = *(const float4*)&wp[i * 1024];

        #pragma unroll
        for (int g2 = 0; g2 < 8; ++g2) {
            #pragma unroll
            for (int i = 0; i < 8; ++i)
                wB[i] = *(const float4*)&wp[((2 * g2 + 1) * 8 + i) * 1024];
            {
                const int k0 = 16 * g2;
                #pragma unroll
                for (int rr = 0; rr < 4; ++rr) {
                    const float4 f0 = *(const float4*)&fr[rr * 128 + k0];
                    const float4 f1 = *(const float4*)&fr[rr * 128 + k0 + 4];
                    fma4(acc[rr], f0.x, wA[0]); fma4(acc[rr], f0.y, wA[1]);
                    fma4(acc[rr], f0.z, wA[2]); fma4(acc[rr], f0.w, wA[3]);
                    fma4(acc[rr], f1.x, wA[4]); fma4(acc[rr], f1.y, wA[5]);
                    fma4(acc[rr], f1.z, wA[6]); fma4(acc[rr], f1.w, wA[7]);
                }
            }
            if (g2 < 7) {
                #pragma unroll
                for (int i = 0; i < 8; ++i)
                    wA[i] = *(const float4*)&wp[((2 * g2 + 2) * 8 + i) * 1024];
            }
            {
                const int k0 = 16 * g2 + 8;
                #pragma unroll
                for (int rr = 0; rr < 4; ++rr) {
                    const float4 f0 = *(const float4*)&fr[rr * 128 + k0];
                    const float4 f1 = *(const float4*)&fr[rr * 128 + k0 + 4];
                    fma4(acc[rr], f0.x, wB[0]); fma4(acc[rr], f0.y, wB[1]);
                    fma4(acc[rr], f0.z, wB[2]); fma4(acc[rr], f0.w, wB[3]);
                    fma4(acc[rr], f1.x, wB[4]); fma4(acc[rr], f1.y, wB[5]);
                    fma4(acc[rr], f1.z, wB[6]); fma4(acc[rr], f1.w, wB[7]);
                }
            }
        }

        const float4 bias = *(const float4*)&bo[c0];
        #pragma unroll
        for (int rr = 0; rr < 4; ++rr) {
            float4 v;
            v.x = mult * (acc[rr].x + bias.x);
            v.y = mult * (acc[rr].y + bias.y);
            v.z = mult * (acc[rr].z + bias.z);
            v.w = mult * (acc[rr].w + bias.w);
            *(float4*)&outp[(r0 + h * 4 + rr) * 1024 + c0] = v;
        }
    } else if (bid == 384) {
        // ================= constants -> ws =================
        const int j = tid & 127;
        const int s = tid >> 7;
        const int k0s = s * 64;
        float* pp    = arena;          // 2*128
        float* pp2   = arena + 256;    // 2*128
        float* sw    = arena + 512;    // 128
        float* kv    = arena + 640;    // 128
        float* wpart = arena + 768;    // 32*8
        {
            float pa = 0.f, pw = 0.f;
            #pragma unroll 32
            for (int k = 0; k < 64; ++k) {
                pa += p.h0[k0s + k] * p.blk_W1[(k0s + k) * 128 + j];
                pw += p.blk_W2[j * 128 + k0s + k] * p.d_W[k0s + k];
            }
            pp[s * 128 + j] = pa; pp2[s * 128 + j] = pw;
        }
        __syncthreads();
        if (s == 0) {
            const float sv = __sinf(pp[j] + pp[128 + j] + p.blk_b1[j])
                           * (pp2[j] + pp2[128 + j]);
            sw[j] = sv;
            kv[j] = (p.h0[j] + p.blk_b2[j]) * p.d_W[j] + sv * p.blk_bc[j];
        }
        __syncthreads();
        {
            const int d  = tid >> 3;          // 0..31
            const int sl = (tid & 7) * 16;
            float acc = 0.f;
            #pragma unroll
            for (int i = 0; i < 16; ++i)
                acc += p.blk_Wc[d * 128 + sl + i] * sw[sl + i];
            wpart[d * 8 + (tid & 7)] = acc;
        }
        __syncthreads();
        if (tid < 32) {
            float w = 0.f;
            #pragma unroll
            for (int q = 0; q < 8; ++q) w += wpart[tid * 8 + q];
            p.ws[tid] = w * (1.0f / 32.0f);
        }
        if (tid < 64) kv[tid] += kv[tid + 64];
        __syncthreads();
        if (tid == 0) {
            float K = p.d_b[0];
            for (int i = 0; i < 64; ++i) K += kv[i];
            p.ws[32] = K;
        }
    }

    // ================= grid barrier =================
    __syncthreads();
    if (tid == 0) {
        __threadfence();
        __hip_atomic_fetch_add(p.bar, 1, __ATOMIC_ACQ_REL, __HIP_MEMORY_SCOPE_AGENT);
        while (__hip_atomic_load(p.bar, __ATOMIC_ACQUIRE, __HIP_MEMORY_SCOPE_AGENT) < NB) {
            __builtin_amdgcn_s_sleep(8);
        }
        __threadfence();
    }
    __syncthreads();

    // ================= u =================
    const int b   = bid >> 7;
    const int rem = bid & 127;
    const int t0  = (rem >> 2) * 8;
    const int x0  = (rem & 3) * 32;
    float4* pxs4 = arena4;             // [32][65]

    if (tid < 32) wcs[tid] = p.ws[tid];
    const float K0 = p.ws[32];
    const int tx = tid & 31;
    const int ty = tid >> 5;           // 0..7
    const float* ztb = p.out_zt + (b * 256 + t0) * 1024;
    const float* pxb = p.out_px + (b * 128 + x0) * 1024;
    __syncthreads();                   // wcs visible; arena safe to reuse

    float acc = 0.f;
    for (int chunk = 0; chunk < 4; ++chunk) {
        const int kc = chunk * 256;
        if (chunk) __syncthreads();
        #pragma unroll
        for (int i = 0; i < 8; ++i) {
            const int m  = tid + 256 * i;
            const int xx = m >> 6;
            const int jf = m & 63;
            float4 v = *(const float4*)&pxb[xx * 1024 + kc + jf * 4];
            const float sc = wcs[(kc >> 5) + (jf >> 3)];
            v.x *= sc; v.y *= sc; v.z *= sc; v.w *= sc;
            pxs4[xx * 65 + jf] = v;
        }
        __syncthreads();

        float4 za[8];
        #pragma unroll
        for (int j2 = 0; j2 < 8; ++j2)
            za[j2] = *(const float4*)&ztb[ty * 1024 + kc + j2 * 4];
        #pragma unroll
        for (int jj = 0; jj < 8; ++jj) {
            float4 nz[8];
            if (jj < 7) {
                const int koff = kc + (jj + 1) * 32;
                #pragma unroll
                for (int j2 = 0; j2 < 8; ++j2)
                    nz[j2] = *(const float4*)&ztb[ty * 1024 + koff + j2 * 4];
            }
            #pragma unroll
            for (int j2 = 0; j2 < 8; ++j2) {
                const float4 q = pxs4[tx * 65 + jj * 8 + j2];
                acc += za[j2].x * q.x + za[j2].y * q.y
                     + za[j2].z * q.z + za[j2].w * q.w;
            }
            if (jj < 7) {
                #pragma unroll
                for (int j2 = 0; j2 < 8; ++j2) za[j2] = nz[j2];
            }
        }
    }
    p.out_u[(b * 256 + t0 + ty) * 128 + x0 + tx] = K0 + acc;
}

extern "C" void kernel_launch(void* const* d_in, const int* in_sizes, int n_in,
                              void* d_out, int out_size, void* d_ws, size_t ws_size,
                              hipStream_t stream) {
    float* out = (float*)d_out;
    float* ws  = (float*)d_ws;
    int*   bar = (int*)(ws + 40);

    P prm;
    prm.x       = (const float*)d_in[0];
    prm.t       = (const float*)d_in[1];
    prm.param   = (const float*)d_in[2];
    prm.p2e_W1  = (const float*)d_in[3];
    prm.p2e_b1  = (const float*)d_in[4];
    prm.p2e_W2  = (const float*)d_in[5];
    prm.p2e_b2  = (const float*)d_in[6];
    prm.e2ex_W  = (const float*)d_in[7];
    prm.e2ex_b  = (const float*)d_in[8];
    prm.e2et_W  = (const float*)d_in[9];
    prm.e2et_b  = (const float*)d_in[10];
    prm.px_Wx   = (const float*)d_in[11];
    prm.px_bx   = (const float*)d_in[12];
    prm.px_We   = (const float*)d_in[13];
    prm.px_be   = (const float*)d_in[14];
    prm.px_Wo   = (const float*)d_in[15];
    prm.px_bo   = (const float*)d_in[16];
    prm.px_mult = (const float*)d_in[17];
    prm.zt_Wx   = (const float*)d_in[18];
    prm.zt_bx   = (const float*)d_in[19];
    prm.zt_We   = (const float*)d_in[20];
    prm.zt_be   = (const float*)d_in[21];
    prm.zt_Wo   = (const float*)d_in[22];
    prm.zt_bo   = (const float*)d_in[23];
    prm.zt_mult = (const float*)d_in[24];
    prm.h0      = (const float*)d_in[25];
    prm.blk_W1  = (const float*)d_in[26];
    prm.blk_b1  = (const float*)d_in[27];
    prm.blk_Wc  = (const float*)d_in[28];
    prm.blk_bc  = (const float*)d_in[29];
    prm.blk_W2  = (const float*)d_in[30];
    prm.blk_b2  = (const float*)d_in[31];
    prm.d_W     = (const float*)d_in[32];
    prm.d_b     = (const float*)d_in[33];
    prm.out_u   = out;                        // 131072
    prm.out_zt  = out + 131072;               // 1048576
    prm.out_px  = out + 131072 + 1048576;     // 524288
    prm.ws      = ws;
    prm.bar     = bar;

    hipMemsetAsync(bar, 0, sizeof(int), stream);
    fused_kernel<<<NB, 256, 0, stream>>>(prm);
}

// Round 10
// 117.732 us; speedup vs baseline: 2.1281x; 2.1281x over previous
//
#include <hip/hip_runtime.h>
#include <math.h>

// B=4, X=128, T=256, HIDDEN=128, EMB=128, DH=32, LATENT=32, K=1024
// Outputs concat: u (131072), zt (1048576), px (524288)
// u[b,t,x] = K0 + sum_k zt[b,t,k]*px[b,x,k]*wc[k>>5]   (wc = wcd/32)
//
// Single fused kernel, 512 blocks x 256 thr, one device barrier.
// ws: [0..31] wc, [32] K0, [40] barrier counter (reset via hipMemsetAsync).
//
// R10 change vs R9: barrier spins with RELAXED atomic loads (no per-iteration
// cache invalidation) + single __threadfence() acquire after exit. R9's
// ACQUIRE-per-iteration spin caused an L2-invalidation storm (290 us, 97% stall).

#define NB 512

struct P {
    const float *x, *t, *param;
    const float *p2e_W1, *p2e_b1, *p2e_W2, *p2e_b2;
    const float *e2ex_W, *e2ex_b, *e2et_W, *e2et_b;
    const float *px_Wx, *px_bx, *px_We, *px_be, *px_Wo, *px_bo, *px_mult;
    const float *zt_Wx, *zt_bx, *zt_We, *zt_be, *zt_Wo, *zt_bo, *zt_mult;
    const float *h0, *blk_W1, *blk_b1, *blk_Wc, *blk_bc, *blk_W2, *blk_b2;
    const float *d_W, *d_b;
    float *out_u, *out_zt, *out_px, *ws;
    int *bar;
};

__device__ __forceinline__ void fma4(float4& a, float s, const float4& v) {
    a.x += s * v.x; a.y += s * v.y; a.z += s * v.z; a.w += s * v.w;
}

__global__ __launch_bounds__(256, 2) void fused_kernel(P p) {
    __shared__ float4 arena4[2080];     // 33.28 KB, phase-aliased
    __shared__ float wcs[32];
    float* arena = (float*)arena4;
    const int tid = threadIdx.x;
    const int bid = blockIdx.x;

    if (bid < 384) {
        // ================= feat =================
        const bool is_zt = bid >= 128;
        const int un = is_zt ? bid - 128 : bid;
        const int rt = un >> 1, cs = un & 1;
        const int r0 = rt * 8;
        const int b = is_zt ? (r0 >> 8) : (r0 >> 7);

        const float* Wh = is_zt ? p.e2et_W : p.e2ex_W;
        const float* bh = is_zt ? p.e2et_b : p.e2ex_b;
        const float* We = is_zt ? p.zt_We : p.px_We;
        const float* be = is_zt ? p.zt_be : p.px_be;
        const float* Wx = is_zt ? p.zt_Wx : p.px_Wx;
        const float* bxv = is_zt ? p.zt_bx : p.px_bx;
        const float* Wo = is_zt ? p.zt_Wo : p.px_Wo;
        const float* bo = is_zt ? p.zt_bo : p.px_bo;
        const float* coord = is_zt ? p.t : p.x;
        const float mult = is_zt ? p.zt_mult[0] : p.px_mult[0];
        float* outp = is_zt ? p.out_zt : p.out_px;

        const int j = tid & 127;
        const int s = tid >> 7;
        const int k0s = s * 64;
        float* hvA = arena;            // 128
        float* hvB = arena + 128;      // 128
        float* pp  = arena + 256;      // 2*128
        float* f   = arena + 512;      // 8*128

        // ---- per-block g chain (2-way k-sliced, batched loads) ----
        if (s == 0) {
            float a = p.p2e_b1[j];
            #pragma unroll
            for (int q = 0; q < 16; ++q)
                a += p.param[b * 16 + q] * p.p2e_W1[q * 128 + j];
            hvA[j] = __sinf(a);
        }
        __syncthreads();
        {
            float acc = 0.f;
            #pragma unroll 32
            for (int k = 0; k < 64; ++k)
                acc += hvA[k0s + k] * p.p2e_W2[(k0s + k) * 128 + j];
            pp[s * 128 + j] = acc;
        }
        __syncthreads();
        if (s == 0) hvB[j] = pp[j] + pp[128 + j] + p.p2e_b2[j];
        __syncthreads();
        {
            float acc = 0.f;
            #pragma unroll 32
            for (int k = 0; k < 64; ++k)
                acc += hvB[k0s + k] * Wh[(k0s + k) * 128 + j];
            pp[s * 128 + j] = acc;
        }
        __syncthreads();
        if (s == 0) hvA[j] = pp[j] + pp[128 + j] + bh[j];
        __syncthreads();
        {
            float acc = 0.f;
            #pragma unroll 32
            for (int k = 0; k < 64; ++k)
                acc += hvA[k0s + k] * We[(k0s + k) * 128 + j];
            pp[s * 128 + j] = acc;
        }
        __syncthreads();
        if (s == 0) {
            const float g = pp[j] + pp[128 + j] + be[j];
            const float wxj = Wx[j], bxj = bxv[j];
            #pragma unroll
            for (int rr = 0; rr < 8; ++rr)
                f[rr * 128 + j] = __sinf(coord[r0 + rr] * wxj + bxj) * g;
        }
        __syncthreads();

        // ---- GEMM 8 rows x 512 cols: thread (c, h): rows h*4..h*4+3 ----
        const int c = tid & 127;
        const int h = tid >> 7;
        const int c0 = cs * 512 + c * 4;
        const float* wp = Wo + c0;
        const float* fr = f + h * 4 * 128;

        float4 acc[4];
        #pragma unroll
        for (int rr = 0; rr < 4; ++rr) acc[rr] = make_float4(0.f, 0.f, 0.f, 0.f);

        float4 wA[8], wB[8];
        #pragma unroll
        for (int i = 0; i < 8; ++i) wA[i] = *(const float4*)&wp[i * 1024];

        #pragma unroll
        for (int g2 = 0; g2 < 8; ++g2) {
            #pragma unroll
            for (int i = 0; i < 8; ++i)
                wB[i] = *(const float4*)&wp[((2 * g2 + 1) * 8 + i) * 1024];
            {
                const int k0 = 16 * g2;
                #pragma unroll
                for (int rr = 0; rr < 4; ++rr) {
                    const float4 f0 = *(const float4*)&fr[rr * 128 + k0];
                    const float4 f1 = *(const float4*)&fr[rr * 128 + k0 + 4];
                    fma4(acc[rr], f0.x, wA[0]); fma4(acc[rr], f0.y, wA[1]);
                    fma4(acc[rr], f0.z, wA[2]); fma4(acc[rr], f0.w, wA[3]);
                    fma4(acc[rr], f1.x, wA[4]); fma4(acc[rr], f1.y, wA[5]);
                    fma4(acc[rr], f1.z, wA[6]); fma4(acc[rr], f1.w, wA[7]);
                }
            }
            if (g2 < 7) {
                #pragma unroll
                for (int i = 0; i < 8; ++i)
                    wA[i] = *(const float4*)&wp[((2 * g2 + 2) * 8 + i) * 1024];
            }
            {
                const int k0 = 16 * g2 + 8;
                #pragma unroll
                for (int rr = 0; rr < 4; ++rr) {
                    const float4 f0 = *(const float4*)&fr[rr * 128 + k0];
                    const float4 f1 = *(const float4*)&fr[rr * 128 + k0 + 4];
                    fma4(acc[rr], f0.x, wB[0]); fma4(acc[rr], f0.y, wB[1]);
                    fma4(acc[rr], f0.z, wB[2]); fma4(acc[rr], f0.w, wB[3]);
                    fma4(acc[rr], f1.x, wB[4]); fma4(acc[rr], f1.y, wB[5]);
                    fma4(acc[rr], f1.z, wB[6]); fma4(acc[rr], f1.w, wB[7]);
                }
            }
        }

        const float4 bias = *(const float4*)&bo[c0];
        #pragma unroll
        for (int rr = 0; rr < 4; ++rr) {
            float4 v;
            v.x = mult * (acc[rr].x + bias.x);
            v.y = mult * (acc[rr].y + bias.y);
            v.z = mult * (acc[rr].z + bias.z);
            v.w = mult * (acc[rr].w + bias.w);
            *(float4*)&outp[(r0 + h * 4 + rr) * 1024 + c0] = v;
        }
    } else if (bid == 384) {
        // ================= constants -> ws =================
        const int j = tid & 127;
        const int s = tid >> 7;
        const int k0s = s * 64;
        float* pp    = arena;          // 2*128
        float* pp2   = arena + 256;    // 2*128
        float* sw    = arena + 512;    // 128
        float* kv    = arena + 640;    // 128
        float* wpart = arena + 768;    // 32*8
        {
            float pa = 0.f, pw = 0.f;
            #pragma unroll 32
            for (int k = 0; k < 64; ++k) {
                pa += p.h0[k0s + k] * p.blk_W1[(k0s + k) * 128 + j];
                pw += p.blk_W2[j * 128 + k0s + k] * p.d_W[k0s + k];
            }
            pp[s * 128 + j] = pa; pp2[s * 128 + j] = pw;
        }
        __syncthreads();
        if (s == 0) {
            const float sv = __sinf(pp[j] + pp[128 + j] + p.blk_b1[j])
                           * (pp2[j] + pp2[128 + j]);
            sw[j] = sv;
            kv[j] = (p.h0[j] + p.blk_b2[j]) * p.d_W[j] + sv * p.blk_bc[j];
        }
        __syncthreads();
        {
            const int d  = tid >> 3;          // 0..31
            const int sl = (tid & 7) * 16;
            float acc = 0.f;
            #pragma unroll
            for (int i = 0; i < 16; ++i)
                acc += p.blk_Wc[d * 128 + sl + i] * sw[sl + i];
            wpart[d * 8 + (tid & 7)] = acc;
        }
        __syncthreads();
        if (tid < 32) {
            float w = 0.f;
            #pragma unroll
            for (int q = 0; q < 8; ++q) w += wpart[tid * 8 + q];
            p.ws[tid] = w * (1.0f / 32.0f);
        }
        if (tid < 64) kv[tid] += kv[tid + 64];
        __syncthreads();
        if (tid == 0) {
            float K = p.d_b[0];
            for (int i = 0; i < 64; ++i) K += kv[i];
            p.ws[32] = K;
        }
    }

    // ================= grid barrier (relaxed spin, acquire once) ==========
    __syncthreads();
    if (tid == 0) {
        __threadfence();   // release our writes
        __hip_atomic_fetch_add(p.bar, 1, __ATOMIC_RELEASE, __HIP_MEMORY_SCOPE_AGENT);
        while (__hip_atomic_load(p.bar, __ATOMIC_RELAXED, __HIP_MEMORY_SCOPE_AGENT) < NB) {
            __builtin_amdgcn_s_sleep(16);
        }
        __threadfence();   // acquire: invalidate caches exactly once
    }
    __syncthreads();

    // ================= u =================
    const int b   = bid >> 7;
    const int rem = bid & 127;
    const int t0  = (rem >> 2) * 8;
    const int x0  = (rem & 3) * 32;
    float4* pxs4 = arena4;             // [32][65]

    if (tid < 32) wcs[tid] = p.ws[tid];
    const float K0 = p.ws[32];
    const int tx = tid & 31;
    const int ty = tid >> 5;           // 0..7
    const float* ztb = p.out_zt + (b * 256 + t0) * 1024;
    const float* pxb = p.out_px + (b * 128 + x0) * 1024;
    __syncthreads();                   // wcs visible; arena safe to reuse

    float acc = 0.f;
    for (int chunk = 0; chunk < 4; ++chunk) {
        const int kc = chunk * 256;
        if (chunk) __syncthreads();
        #pragma unroll
        for (int i = 0; i < 8; ++i) {
            const int m  = tid + 256 * i;
            const int xx = m >> 6;
            const int jf = m & 63;
            float4 v = *(const float4*)&pxb[xx * 1024 + kc + jf * 4];
            const float sc = wcs[(kc >> 5) + (jf >> 3)];
            v.x *= sc; v.y *= sc; v.z *= sc; v.w *= sc;
            pxs4[xx * 65 + jf] = v;
        }
        __syncthreads();

        float4 za[8];
        #pragma unroll
        for (int j2 = 0; j2 < 8; ++j2)
            za[j2] = *(const float4*)&ztb[ty * 1024 + kc + j2 * 4];
        #pragma unroll
        for (int jj = 0; jj < 8; ++jj) {
            float4 nz[8];
            if (jj < 7) {
                const int koff = kc + (jj + 1) * 32;
                #pragma unroll
                for (int j2 = 0; j2 < 8; ++j2)
                    nz[j2] = *(const float4*)&ztb[ty * 1024 + koff + j2 * 4];
            }
            #pragma unroll
            for (int j2 = 0; j2 < 8; ++j2) {
                const float4 q = pxs4[tx * 65 + jj * 8 + j2];
                acc += za[j2].x * q.x + za[j2].y * q.y
                     + za[j2].z * q.z + za[j2].w * q.w;
            }
            if (jj < 7) {
                #pragma unroll
                for (int j2 = 0; j2 < 8; ++j2) za[j2] = nz[j2];
            }
        }
    }
    p.out_u[(b * 256 + t0 + ty) * 128 + x0 + tx] = K0 + acc;
}

extern "C" void kernel_launch(void* const* d_in, const int* in_sizes, int n_in,
                              void* d_out, int out_size, void* d_ws, size_t ws_size,
                              hipStream_t stream) {
    float* out = (float*)d_out;
    float* ws  = (float*)d_ws;
    int*   bar = (int*)(ws + 40);

    P prm;
    prm.x       = (const float*)d_in[0];
    prm.t       = (const float*)d_in[1];
    prm.param   = (const float*)d_in[2];
    prm.p2e_W1  = (const float*)d_in[3];
    prm.p2e_b1  = (const float*)d_in[4];
    prm.p2e_W2  = (const float*)d_in[5];
    prm.p2e_b2  = (const float*)d_in[6];
    prm.e2ex_W  = (const float*)d_in[7];
    prm.e2ex_b  = (const float*)d_in[8];
    prm.e2et_W  = (const float*)d_in[9];
    prm.e2et_b  = (const float*)d_in[10];
    prm.px_Wx   = (const float*)d_in[11];
    prm.px_bx   = (const float*)d_in[12];
    prm.px_We   = (const float*)d_in[13];
    prm.px_be   = (const float*)d_in[14];
    prm.px_Wo   = (const float*)d_in[15];
    prm.px_bo   = (const float*)d_in[16];
    prm.px_mult = (const float*)d_in[17];
    prm.zt_Wx   = (const float*)d_in[18];
    prm.zt_bx   = (const float*)d_in[19];
    prm.zt_We   = (const float*)d_in[20];
    prm.zt_be   = (const float*)d_in[21];
    prm.zt_Wo   = (const float*)d_in[22];
    prm.zt_bo   = (const float*)d_in[23];
    prm.zt_mult = (const float*)d_in[24];
    prm.h0      = (const float*)d_in[25];
    prm.blk_W1  = (const float*)d_in[26];
    prm.blk_b1  = (const float*)d_in[27];
    prm.blk_Wc  = (const float*)d_in[28];
    prm.blk_bc  = (const float*)d_in[29];
    prm.blk_W2  = (const float*)d_in[30];
    prm.blk_b2  = (const float*)d_in[31];
    prm.d_W     = (const float*)d_in[32];
    prm.d_b     = (const float*)d_in[33];
    prm.out_u   = out;                        // 131072
    prm.out_zt  = out + 131072;               // 1048576
    prm.out_px  = out + 131072 + 1048576;     // 524288
    prm.ws      = ws;
    prm.bar     = bar;

    hipMemsetAsync(bar, 0, sizeof(int), stream);
    fused_kernel<<<NB, 256, 0, stream>>>(prm);
}

// Round 11
// 42.478 us; speedup vs baseline: 5.8982x; 2.7716x over previous
//
#include <hip/hip_runtime.h>
#include <math.h>

// B=4, X=128, T=256, HIDDEN=128, EMB=128, DH=32, LATENT=32, K=1024
// Outputs concat: u (131072), zt (1048576), px (524288)
// u[b,t,x] = K0 + sum_k zt[b,t,k]*px[b,x,k]*wc[k>>5]   (wc = wcd/32)
//
// Two kernels (split at the old barrier point; stream-ordered):
//   feat_kernel: 385 blocks x 256 thr. bid<384 = feat unit (g-chain via
//     float4-row-sliced GEMVs + 8x512 GEMM with register dbuf); bid==384 =
//     constants -> ws[0..31]=wc, ws[32]=K0.
//   u_kernel: 512 blocks x 256 thr (R9 u phase, validated).

struct P {
    const float *x, *t, *param;
    const float *p2e_W1, *p2e_b1, *p2e_W2, *p2e_b2;
    const float *e2ex_W, *e2ex_b, *e2et_W, *e2et_b;
    const float *px_Wx, *px_bx, *px_We, *px_be, *px_Wo, *px_bo, *px_mult;
    const float *zt_Wx, *zt_bx, *zt_We, *zt_be, *zt_Wo, *zt_bo, *zt_mult;
    const float *h0, *blk_W1, *blk_b1, *blk_Wc, *blk_bc, *blk_W2, *blk_b2;
    const float *d_W, *d_b;
    float *out_u, *out_zt, *out_px, *ws;
};

__device__ __forceinline__ void fma4(float4& a, float s, const float4& v) {
    a.x += s * v.x; a.y += s * v.y; a.z += s * v.z; a.w += s * v.w;
}

// One 128->128 GEMV stage, float4-row-sliced:
// out[j] = bias[j] + sum_k vin[k] * W[k*128+j]
// thread (j4=tid&31, sl=tid>>5): 16 contiguous float4 loads (batchable).
__device__ __forceinline__ void gemv_stage(
    const float* __restrict__ W, const float* __restrict__ bias,
    const float* vin, float* vout, float* partf, int tid)
{
    const int j4 = tid & 31;
    const int sl = tid >> 5;
    float4 a4 = make_float4(0.f, 0.f, 0.f, 0.f);
    const float* Wp = W + sl * 16 * 128 + j4 * 4;
    #pragma unroll
    for (int k = 0; k < 16; ++k)
        fma4(a4, vin[sl * 16 + k], *(const float4*)&Wp[k * 128]);
    *(float4*)&partf[sl * 128 + j4 * 4] = a4;
    __syncthreads();
    if (tid < 128) {
        float v = bias[tid];
        #pragma unroll
        for (int q = 0; q < 8; ++q) v += partf[q * 128 + tid];
        vout[tid] = v;
    }
    __syncthreads();
}

__global__ __launch_bounds__(256, 2) void feat_kernel(P p) {
    __shared__ float vin[128], vout[128];
    __shared__ float partf[1024];
    __shared__ float f[8 * 128];
    const int tid = threadIdx.x;
    const int bid = blockIdx.x;

    if (bid < 384) {
        const bool is_zt = bid >= 128;
        const int un = is_zt ? bid - 128 : bid;
        const int rt = un >> 1, cs = un & 1;
        const int r0 = rt * 8;
        const int b = is_zt ? (r0 >> 8) : (r0 >> 7);

        const float* Wh = is_zt ? p.e2et_W : p.e2ex_W;
        const float* bh = is_zt ? p.e2et_b : p.e2ex_b;
        const float* We = is_zt ? p.zt_We : p.px_We;
        const float* be = is_zt ? p.zt_be : p.px_be;
        const float* Wx = is_zt ? p.zt_Wx : p.px_Wx;
        const float* bxv = is_zt ? p.zt_bx : p.px_bx;
        const float* Wo = is_zt ? p.zt_Wo : p.px_Wo;
        const float* bo = is_zt ? p.zt_bo : p.px_bo;
        const float* coord = is_zt ? p.t : p.x;
        const float mult = is_zt ? p.zt_mult[0] : p.px_mult[0];
        float* outp = is_zt ? p.out_zt : p.out_px;

        // ---- g-chain: 4 stages, all load-batched ----
        if (tid < 128) {
            float a = p.p2e_b1[tid];
            #pragma unroll
            for (int q = 0; q < 16; ++q)
                a += p.param[b * 16 + q] * p.p2e_W1[q * 128 + tid];
            vin[tid] = __sinf(a);
        }
        __syncthreads();
        gemv_stage(p.p2e_W2, p.p2e_b2, vin, vout, partf, tid);   // e
        gemv_stage(Wh, bh, vout, vin, partf, tid);               // ex/et
        gemv_stage(We, be, vin, vout, partf, tid);               // g
        if (tid < 128) {
            const float g = vout[tid];
            const float wxj = Wx[tid], bxj = bxv[tid];
            #pragma unroll
            for (int rr = 0; rr < 8; ++rr)
                f[rr * 128 + tid] = __sinf(coord[r0 + rr] * wxj + bxj) * g;
        }
        __syncthreads();

        // ---- GEMM 8 rows x 512 cols; thread (c=tid&127, h=tid>>7) ----
        const int c = tid & 127;
        const int h = tid >> 7;
        const int c0 = cs * 512 + c * 4;
        const float* wp = Wo + c0;
        const float* fr = f + h * 4 * 128;

        float4 acc[4];
        #pragma unroll
        for (int rr = 0; rr < 4; ++rr) acc[rr] = make_float4(0.f, 0.f, 0.f, 0.f);

        float4 wA[8], wB[8];
        #pragma unroll
        for (int i = 0; i < 8; ++i) wA[i] = *(const float4*)&wp[i * 1024];

        #pragma unroll
        for (int g2 = 0; g2 < 8; ++g2) {
            #pragma unroll
            for (int i = 0; i < 8; ++i)
                wB[i] = *(const float4*)&wp[((2 * g2 + 1) * 8 + i) * 1024];
            {
                const int k0 = 16 * g2;
                #pragma unroll
                for (int rr = 0; rr < 4; ++rr) {
                    const float4 f0 = *(const float4*)&fr[rr * 128 + k0];
                    const float4 f1 = *(const float4*)&fr[rr * 128 + k0 + 4];
                    fma4(acc[rr], f0.x, wA[0]); fma4(acc[rr], f0.y, wA[1]);
                    fma4(acc[rr], f0.z, wA[2]); fma4(acc[rr], f0.w, wA[3]);
                    fma4(acc[rr], f1.x, wA[4]); fma4(acc[rr], f1.y, wA[5]);
                    fma4(acc[rr], f1.z, wA[6]); fma4(acc[rr], f1.w, wA[7]);
                }
            }
            if (g2 < 7) {
                #pragma unroll
                for (int i = 0; i < 8; ++i)
                    wA[i] = *(const float4*)&wp[((2 * g2 + 2) * 8 + i) * 1024];
            }
            {
                const int k0 = 16 * g2 + 8;
                #pragma unroll
                for (int rr = 0; rr < 4; ++rr) {
                    const float4 f0 = *(const float4*)&fr[rr * 128 + k0];
                    const float4 f1 = *(const float4*)&fr[rr * 128 + k0 + 4];
                    fma4(acc[rr], f0.x, wB[0]); fma4(acc[rr], f0.y, wB[1]);
                    fma4(acc[rr], f0.z, wB[2]); fma4(acc[rr], f0.w, wB[3]);
                    fma4(acc[rr], f1.x, wB[4]); fma4(acc[rr], f1.y, wB[5]);
                    fma4(acc[rr], f1.z, wB[6]); fma4(acc[rr], f1.w, wB[7]);
                }
            }
        }

        const float4 bias = *(const float4*)&bo[c0];
        #pragma unroll
        for (int rr = 0; rr < 4; ++rr) {
            float4 v;
            v.x = mult * (acc[rr].x + bias.x);
            v.y = mult * (acc[rr].y + bias.y);
            v.z = mult * (acc[rr].z + bias.z);
            v.w = mult * (acc[rr].w + bias.w);
            *(float4*)&outp[(r0 + h * 4 + rr) * 1024 + c0] = v;
        }
    } else {
        // ================= constants -> ws =================
        __shared__ float dws[128];
        if (tid < 128) { vin[tid] = p.h0[tid]; dws[tid] = p.d_W[tid]; }
        __syncthreads();
        gemv_stage(p.blk_W1, p.blk_b1, vin, vout, partf, tid);   // sacc
        if (tid < 128) {
            float w2 = 0.f;
            const float4* rp = (const float4*)&p.blk_W2[tid * 128];
            #pragma unroll
            for (int m4 = 0; m4 < 32; ++m4) {
                const float4 wv = rp[m4];
                const float4 dv = *(const float4*)&dws[m4 * 4];
                w2 += wv.x * dv.x + wv.y * dv.y + wv.z * dv.z + wv.w * dv.w;
            }
            const float sv = __sinf(vout[tid]) * w2;
            vin[tid] = sv;                                   // sw
            vout[tid] = (p.h0[tid] + p.blk_b2[tid]) * dws[tid] + sv * p.blk_bc[tid];
        }
        __syncthreads();
        {
            const int d  = tid >> 3;          // 0..31
            const int sg = (tid & 7) * 16;
            float acc = 0.f;
            #pragma unroll
            for (int i4 = 0; i4 < 4; ++i4) {
                const float4 wv = *(const float4*)&p.blk_Wc[d * 128 + sg + i4 * 4];
                const float4 sv = *(const float4*)&vin[sg + i4 * 4];
                acc += wv.x * sv.x + wv.y * sv.y + wv.z * sv.z + wv.w * sv.w;
            }
            partf[d * 8 + (tid & 7)] = acc;
        }
        __syncthreads();
        if (tid < 32) {
            float w = 0.f;
            #pragma unroll
            for (int q = 0; q < 8; ++q) w += partf[tid * 8 + q];
            p.ws[tid] = w * (1.0f / 32.0f);
        }
        if (tid < 64) vout[tid] += vout[tid + 64];
        __syncthreads();
        if (tid == 0) {
            float K = p.d_b[0];
            #pragma unroll
            for (int i = 0; i < 64; ++i) K += vout[i];
            p.ws[32] = K;
        }
    }
}

__global__ __launch_bounds__(256, 2) void u_kernel(
    const float* __restrict__ zt, const float* __restrict__ px,
    const float* __restrict__ ws, float* __restrict__ out_u)
{
    __shared__ float4 pxs4[2080];      // [32][65]
    __shared__ float wcs[32];
    const int tid = threadIdx.x;
    const int bid = blockIdx.x;
    const int b   = bid >> 7;
    const int rem = bid & 127;
    const int t0  = (rem >> 2) * 8;
    const int x0  = (rem & 3) * 32;

    if (tid < 32) wcs[tid] = ws[tid];
    const float K0 = ws[32];
    const int tx = tid & 31;
    const int ty = tid >> 5;           // 0..7
    const float* ztb = zt + (b * 256 + t0) * 1024;
    const float* pxb = px + (b * 128 + x0) * 1024;
    __syncthreads();

    float acc = 0.f;
    for (int chunk = 0; chunk < 4; ++chunk) {
        const int kc = chunk * 256;
        if (chunk) __syncthreads();
        #pragma unroll
        for (int i = 0; i < 8; ++i) {
            const int m  = tid + 256 * i;
            const int xx = m >> 6;
            const int jf = m & 63;
            float4 v = *(const float4*)&pxb[xx * 1024 + kc + jf * 4];
            const float sc = wcs[(kc >> 5) + (jf >> 3)];
            v.x *= sc; v.y *= sc; v.z *= sc; v.w *= sc;
            pxs4[xx * 65 + jf] = v;
        }
        __syncthreads();

        float4 za[8];
        #pragma unroll
        for (int j2 = 0; j2 < 8; ++j2)
            za[j2] = *(const float4*)&ztb[ty * 1024 + kc + j2 * 4];
        #pragma unroll
        for (int jj = 0; jj < 8; ++jj) {
            float4 nz[8];
            if (jj < 7) {
                const int koff = kc + (jj + 1) * 32;
                #pragma unroll
                for (int j2 = 0; j2 < 8; ++j2)
                    nz[j2] = *(const float4*)&ztb[ty * 1024 + koff + j2 * 4];
            }
            #pragma unroll
            for (int j2 = 0; j2 < 8; ++j2) {
                const float4 q = pxs4[tx * 65 + jj * 8 + j2];
                acc += za[j2].x * q.x + za[j2].y * q.y
                     + za[j2].z * q.z + za[j2].w * q.w;
            }
            if (jj < 7) {
                #pragma unroll
                for (int j2 = 0; j2 < 8; ++j2) za[j2] = nz[j2];
            }
        }
    }
    out_u[(b * 256 + t0 + ty) * 128 + x0 + tx] = K0 + acc;
}

extern "C" void kernel_launch(void* const* d_in, const int* in_sizes, int n_in,
                              void* d_out, int out_size, void* d_ws, size_t ws_size,
                              hipStream_t stream) {
    float* out = (float*)d_out;
    float* ws  = (float*)d_ws;

    P prm;
    prm.x       = (const float*)d_in[0];
    prm.t       = (const float*)d_in[1];
    prm.param   = (const float*)d_in[2];
    prm.p2e_W1  = (const float*)d_in[3];
    prm.p2e_b1  = (const float*)d_in[4];
    prm.p2e_W2  = (const float*)d_in[5];
    prm.p2e_b2  = (const float*)d_in[6];
    prm.e2ex_W  = (const float*)d_in[7];
    prm.e2ex_b  = (const float*)d_in[8];
    prm.e2et_W  = (const float*)d_in[9];
    prm.e2et_b  = (const float*)d_in[10];
    prm.px_Wx   = (const float*)d_in[11];
    prm.px_bx   = (const float*)d_in[12];
    prm.px_We   = (const float*)d_in[13];
    prm.px_be   = (const float*)d_in[14];
    prm.px_Wo   = (const float*)d_in[15];
    prm.px_bo   = (const float*)d_in[16];
    prm.px_mult = (const float*)d_in[17];
    prm.zt_Wx   = (const float*)d_in[18];
    prm.zt_bx   = (const float*)d_in[19];
    prm.zt_We   = (const float*)d_in[20];
    prm.zt_be   = (const float*)d_in[21];
    prm.zt_Wo   = (const float*)d_in[22];
    prm.zt_bo   = (const float*)d_in[23];
    prm.zt_mult = (const float*)d_in[24];
    prm.h0      = (const float*)d_in[25];
    prm.blk_W1  = (const float*)d_in[26];
    prm.blk_b1  = (const float*)d_in[27];
    prm.blk_Wc  = (const float*)d_in[28];
    prm.blk_bc  = (const float*)d_in[29];
    prm.blk_W2  = (const float*)d_in[30];
    prm.blk_b2  = (const float*)d_in[31];
    prm.d_W     = (const float*)d_in[32];
    prm.d_b     = (const float*)d_in[33];
    prm.out_u   = out;                        // 131072
    prm.out_zt  = out + 131072;               // 1048576
    prm.out_px  = out + 131072 + 1048576;     // 524288
    prm.ws      = ws;

    feat_kernel<<<385, 256, 0, stream>>>(prm);
    u_kernel<<<512, 256, 0, stream>>>(prm.out_zt, prm.out_px, ws, out);
}